// Round 9
// baseline (1640.924 us; speedup 1.0000x reference)
//
#include <hip/hip_runtime.h>
#include <stdint.h>
#include <stddef.h>

typedef __bf16 bf16;
typedef __bf16 bf16x8 __attribute__((ext_vector_type(8)));
typedef float  f32x4  __attribute__((ext_vector_type(4)));

typedef __attribute__((address_space(3))) void       lds_void;
typedef __attribute__((address_space(1))) const void gbl_cvoid;

#define ASYNC_CP16(g, l) \
  __builtin_amdgcn_global_load_lds((gbl_cvoid*)(g), (lds_void*)(l), 16, 0, 0)

#define GRID 1024

__device__ __forceinline__ int swz(int r) { return (r & 7) ^ ((r & 8) >> 1); }

// Software grid barrier (single-use counter per sync point; counters zeroed
// by hipMemsetAsync each call). RELEASE add + ACQUIRE spin at agent scope:
// same protocol as cg::grid.sync, but no cooperative-launch validation to
// fail. Co-residency of all 1024 blocks is guaranteed by resources:
// LDS 34816B -> 4 blk/CU, launch_bounds(256,4) -> VGPR<=128 -> 4 blk/CU.
__device__ __forceinline__ void gbar(unsigned* cnt)
{
  __syncthreads();
  if (threadIdx.x == 0) {
    __threadfence();
    __hip_atomic_fetch_add(cnt, 1u, __ATOMIC_RELEASE, __HIP_MEMORY_SCOPE_AGENT);
    while (__hip_atomic_load(cnt, __ATOMIC_ACQUIRE, __HIP_MEMORY_SCOPE_AGENT) < GRID) {
      __builtin_amdgcn_s_sleep(16);
    }
  }
  __syncthreads();
}

struct MegaArgs {
  const int*   adj;
  const float *hf, *Wq, *Wk, *Wv, *Wo, *W1, *W2;
  const float *bq, *bk, *bv, *bo, *b1, *b2, *g1, *be1, *g2, *be2;
  bf16 *hb, *Wqb, *Wkb, *Wvb, *Wob, *W1b, *W2b;
  bf16 *q, *k, *vt;
  unsigned long long* mb;
  bf16 *ctx, *Opart;
  float *Lpart, *skP;
  bf16 *h1, *ff1;
  float* out;
  unsigned* bars;
};

// ---------------------------------------------------------------------------
// MT=64 async-staged GEMM core: 64x128 tile, 4 waves (1x4), acc 4x2, BK=64.
// ---------------------------------------------------------------------------
__device__ __forceinline__ void gemm64(
    const bf16* A, const bf16* B, bf16* As, bf16* Bs,
    f32x4 (&acc)[4][2], int K, int m0, int n0, int kbeg, int kend)
{
  const int tid    = threadIdx.x;
  const int lane   = tid & 63;
  const int wave   = tid >> 6;
  const int lane15 = lane & 15;
  const int quad   = lane >> 4;
  const int wn     = wave << 5;

  int srA[2], soA[2], srB[4], soB[4];
#pragma unroll
  for (int i = 0; i < 2; ++i) {
    int c  = ((wave * 2 + i) << 6) + lane;
    srA[i] = c >> 3;
    soA[i] = ((c & 7) ^ swz(srA[i])) * 8;
  }
#pragma unroll
  for (int i = 0; i < 4; ++i) {
    int c  = ((wave * 4 + i) << 6) + lane;
    srB[i] = c >> 3;
    soB[i] = ((c & 7) ^ swz(srB[i])) * 8;
  }

  const bf16* Ab = A + (size_t)m0 * K;
  const bf16* Bb = B + (size_t)n0 * K;

  for (int k0 = kbeg; k0 < kend; k0 += 64) {
#pragma unroll
    for (int i = 0; i < 2; ++i)
      ASYNC_CP16(Ab + (size_t)srA[i] * K + k0 + soA[i], &As[(wave * 2 + i) * 512]);
#pragma unroll
    for (int i = 0; i < 4; ++i)
      ASYNC_CP16(Bb + (size_t)srB[i] * K + k0 + soB[i], &Bs[(wave * 4 + i) * 512]);
    __syncthreads();

#pragma unroll
    for (int kk = 0; kk < 2; ++kk) {
      bf16x8 af[4], bfr[2];
#pragma unroll
      for (int f = 0; f < 4; ++f) {
        const int ra = f * 16 + lane15;
        af[f] = *(const bf16x8*)&As[ra * 64 + (((kk * 4 + quad) ^ swz(ra)) * 8)];
      }
#pragma unroll
      for (int f = 0; f < 2; ++f) {
        const int rb = wn + f * 16 + lane15;
        bfr[f] = *(const bf16x8*)&Bs[rb * 64 + (((kk * 4 + quad) ^ swz(rb)) * 8)];
      }
#pragma unroll
      for (int fm = 0; fm < 4; ++fm)
#pragma unroll
        for (int fn = 0; fn < 2; ++fn)
          acc[fm][fn] = __builtin_amdgcn_mfma_f32_16x16x32_bf16(
              af[fm], bfr[fn], acc[fm][fn], 0, 0, 0);
    }
    __syncthreads();
  }
}

// ---------------------------------------------------------------------------
// split-K combine + bias + residual + LayerNorm (N=512), one row per wave x4.
// ---------------------------------------------------------------------------
template <int F32OUT>
__device__ __forceinline__ void addln_body(
    int vb, const bf16* x, const float* Cp, const float* bias,
    const float* gam, const float* bet, void* out)
{
  const int wave = threadIdx.x >> 6, lane = threadIdx.x & 63;
  const int row  = vb * 4 + wave;
  const size_t base = (size_t)row * 512 + lane * 8;
  const int col = lane * 8;
  bf16x8 xv = *(const bf16x8*)(x + base);
  const float* p0 = Cp + base;
  const float* p1 = Cp + (size_t)4096 * 512 + base;
  f32x4 a0 = *(const f32x4*)p0, a1 = *(const f32x4*)(p0 + 4);
  f32x4 b0 = *(const f32x4*)p1, b1 = *(const f32x4*)(p1 + 4);
  f32x4 c0 = *(const f32x4*)(bias + col), c1 = *(const f32x4*)(bias + col + 4);
  float v[8], s = 0.0f, s2 = 0.0f;
#pragma unroll
  for (int j = 0; j < 4; ++j) {
    v[j]     = (float)xv[j]     + a0[j] + b0[j] + c0[j];
    v[4 + j] = (float)xv[4 + j] + a1[j] + b1[j] + c1[j];
  }
#pragma unroll
  for (int j = 0; j < 8; ++j) { s += v[j]; s2 += v[j] * v[j]; }
#pragma unroll
  for (int d = 1; d < 64; d <<= 1) { s += __shfl_xor(s, d, 64); s2 += __shfl_xor(s2, d, 64); }
  const float mu  = s * (1.0f / 512.0f);
  const float var = s2 * (1.0f / 512.0f) - mu * mu;
  const float rs  = rsqrtf(var + 1e-5f);
  f32x4 g0 = *(const f32x4*)(gam + col), g1 = *(const f32x4*)(gam + col + 4);
  f32x4 e0 = *(const f32x4*)(bet + col), e1 = *(const f32x4*)(bet + col + 4);
  if (F32OUT) {
    float* o = (float*)out + base;
#pragma unroll
    for (int j = 0; j < 4; ++j) {
      o[j]     = ((v[j] - mu) * rs) * g0[j] + e0[j];
      o[4 + j] = ((v[4 + j] - mu) * rs) * g1[j] + e1[j];
    }
  } else {
    bf16x8 ov;
#pragma unroll
    for (int j = 0; j < 4; ++j) {
      ov[j]     = (bf16)(((v[j] - mu) * rs) * g0[j] + e0[j]);
      ov[4 + j] = (bf16)(((v[4 + j] - mu) * rs) * g1[j] + e1[j]);
    }
    *(bf16x8*)((bf16*)out + base) = ov;
  }
}

// ---------------------------------------------------------------------------
// The mega-kernel: 9 stages, 8 software grid barriers, one normal launch.
// ---------------------------------------------------------------------------
__global__ __launch_bounds__(256, 4) void k_mega(MegaArgs a)
{
  __shared__ __align__(16) char smem[34816];
  bf16* As  = (bf16*)smem;             // 8 KB   (GEMM A / attn Ks)
  bf16* Bs  = (bf16*)(smem + 8192);    // 16 KB  (GEMM B / attn Vs)
  bf16* Plb = (bf16*)(smem + 16384);   // 18 KB  (attn P, 4 waves x 32x72)

  const int bid    = blockIdx.x;
  const int tid    = threadIdx.x;
  const int lane   = tid & 63;
  const int wave   = tid >> 6;
  const int lane15 = lane & 15;
  const int quad   = lane >> 4;

  // ---- S0: pack adjacency(+I) into bitmask + fp32->bf16 cast --------------
  for (int vb = bid; vb < 68096; vb += GRID) {
    if (vb < 65536) {
      const int gw = vb * 4 + wave;
      const int av = a.adj[(size_t)gw * 64 + lane];
      unsigned long long m = __ballot(av != 0);
      const int row = gw >> 6, wc = gw & 63;
      if ((row >> 6) == wc) m |= 1ull << (row & 63);
      if (lane == 0) a.mb[gw] = m;
    } else {
      const int t = vb - 65536;
      const float* src; bf16* dst; int i;
      if (t < 1024)      { src = a.hf; dst = a.hb;  i = t * 256 + tid; }
      else if (t < 1152) { src = a.Wq; dst = a.Wqb; i = (t - 1024) * 256 + tid; }
      else if (t < 1280) { src = a.Wk; dst = a.Wkb; i = (t - 1152) * 256 + tid; }
      else if (t < 1408) { src = a.Wv; dst = a.Wvb; i = (t - 1280) * 256 + tid; }
      else if (t < 1536) { src = a.Wo; dst = a.Wob; i = (t - 1408) * 256 + tid; }
      else if (t < 2048) { src = a.W1; dst = a.W1b; i = (t - 1536) * 256 + tid; }
      else               { src = a.W2; dst = a.W2b; i = (t - 2048) * 256 + tid; }
      const float4* s = (const float4*)src + (size_t)i * 2;
      const float4 x0 = s[0], x1 = s[1];
      bf16x8 y;
      y[0] = (bf16)x0.x; y[1] = (bf16)x0.y; y[2] = (bf16)x0.z; y[3] = (bf16)x0.w;
      y[4] = (bf16)x1.x; y[5] = (bf16)x1.y; y[6] = (bf16)x1.z; y[7] = (bf16)x1.w;
      *(bf16x8*)(dst + (size_t)i * 8) = y;
    }
  }
  gbar(a.bars + 0);

  // ---- S1: QKV projection (concat W [1536,512]); V blocks write vt --------
  for (int vb = bid; vb < 768; vb += GRID) {
    const int m0 = (vb & 63) * 64, n0 = (vb >> 6) * 128;
    f32x4 acc[4][2] = {};
    gemm64(a.hb, a.Wqb, As, Bs, acc, 512, m0, n0, 0, 512);
    const int wn = wave << 5;
    const int proj = n0 >> 9;
    const int ncol0 = n0 & 511;
    const float* bias = (proj == 0) ? a.bq : (proj == 1) ? a.bk : a.bv;
    if (proj < 2) {
      bf16* C = proj ? a.k : a.q;
#pragma unroll
      for (int fm = 0; fm < 4; ++fm)
#pragma unroll
        for (int fn = 0; fn < 2; ++fn) {
          const int col = ncol0 + wn + fn * 16 + lane15;
          const float bvv = bias[col];
#pragma unroll
          for (int r = 0; r < 4; ++r) {
            const int row = m0 + fm * 16 + quad * 4 + r;
            C[(size_t)row * 512 + col] = (bf16)(acc[fm][fn][r] + bvv);
          }
        }
    } else {
      __syncthreads();   // K-loop LDS dead
      bf16* SM = As;     // transpose scratch: 128*72*2 = 18432B < 34816B
#pragma unroll
      for (int fm = 0; fm < 4; ++fm)
#pragma unroll
        for (int fn = 0; fn < 2; ++fn) {
          const int colL = wn + fn * 16 + lane15;
          const float bvv = bias[ncol0 + colL];
#pragma unroll
          for (int r = 0; r < 4; ++r) {
            const int rowL = fm * 16 + quad * 4 + r;
            SM[colL * 72 + rowL] = (bf16)(acc[fm][fn][r] + bvv);
          }
        }
      __syncthreads();
#pragma unroll
      for (int i = 0; i < 4; ++i) {
        const int c = i * 256 + tid;
        const int colL = c >> 3, rw = (c & 7) * 8;
        *(bf16x8*)&a.vt[(size_t)(ncol0 + colL) * 4096 + m0 + rw] =
            *(const bf16x8*)&SM[colL * 72 + rw];
      }
      __syncthreads();
    }
  }
  gbar(a.bars + 1);

  // ---- S2: flash attention, split-K x4, 32 q-rows/wave --------------------
  {
    const int vb = bid;
    bf16* Ks = As;
    bf16* Vs = Bs;
    const int sp = vb & 3;
    const int hd = (vb >> 2) & 7;
    const int qt = vb >> 5;
    const int qrow = qt * 128 + wave * 32;

    bf16x8 qf[2][2];
#pragma unroll
    for (int mt = 0; mt < 2; ++mt)
#pragma unroll
      for (int c = 0; c < 2; ++c)
        qf[mt][c] = *(const bf16x8*)&a.q[(size_t)(qrow + mt * 16 + lane15) * 512 +
                                         hd * 64 + c * 32 + quad * 8];

    int srK[2], soK[2];
#pragma unroll
    for (int i = 0; i < 2; ++i) {
      int c  = ((wave * 2 + i) << 6) + lane;
      srK[i] = c >> 3;
      soK[i] = ((c & 7) ^ swz(srK[i])) * 8;
    }
    const bf16* KmB[2] = {
        a.k + (size_t)srK[0] * 512 + hd * 64 + soK[0],
        a.k + (size_t)srK[1] * 512 + hd * 64 + soK[1]};
    const bf16* VtB[2] = {
        a.vt + (size_t)(hd * 64 + srK[0]) * 4096 + soK[0],
        a.vt + (size_t)(hd * 64 + srK[1]) * 4096 + soK[1]};

    bf16x8 ones;
#pragma unroll
    for (int j = 0; j < 8; ++j) ones[j] = (bf16)1.0f;

    f32x4 o[2][4] = {};
    f32x4 la[2]   = {};

    for (int kt = sp * 16; kt < sp * 16 + 16; ++kt) {
      const int kb = kt * 64;
#pragma unroll
      for (int i = 0; i < 2; ++i) {
        ASYNC_CP16(KmB[i] + (size_t)kb * 512, &Ks[(wave * 2 + i) * 512]);
        ASYNC_CP16(VtB[i] + kb,               &Vs[(wave * 2 + i) * 512]);
      }
      __syncthreads();

      unsigned long long mw[2][4];
#pragma unroll
      for (int mt = 0; mt < 2; ++mt)
#pragma unroll
        for (int r = 0; r < 4; ++r)
          mw[mt][r] = a.mb[(size_t)(qrow + mt * 16 + quad * 4 + r) * 64 + kt] >> lane15;

#pragma unroll
      for (int g = 0; g < 4; ++g) {
        const int row = g * 16 + lane15;
        bf16x8 k0f = *(const bf16x8*)&Ks[row * 64 + ((quad       ^ swz(row)) * 8)];
        bf16x8 k1f = *(const bf16x8*)&Ks[row * 64 + (((4 + quad) ^ swz(row)) * 8)];
#pragma unroll
        for (int mt = 0; mt < 2; ++mt) {
          f32x4 s = {};
          s = __builtin_amdgcn_mfma_f32_16x16x32_bf16(qf[mt][0], k0f, s, 0, 0, 0);
          s = __builtin_amdgcn_mfma_f32_16x16x32_bf16(qf[mt][1], k1f, s, 0, 0, 0);
#pragma unroll
          for (int r = 0; r < 4; ++r) {
            const bool ok = ((mw[mt][r] >> (g * 16)) & 1ull) != 0;
            const float p = ok ? __expf(s[r] * 0.125f) : 0.0f;
            Plb[wave * 2304 + (mt * 16 + quad * 4 + r) * 72 + g * 16 + lane15] = (bf16)p;
          }
        }
      }

#pragma unroll
      for (int c2 = 0; c2 < 2; ++c2) {
        bf16x8 vf[4];
#pragma unroll
        for (int g2 = 0; g2 < 4; ++g2) {
          const int row = g2 * 16 + lane15;
          vf[g2] = *(const bf16x8*)&Vs[row * 64 + (((c2 * 4 + quad) ^ swz(row)) * 8)];
        }
#pragma unroll
        for (int mt = 0; mt < 2; ++mt) {
          bf16x8 pa = *(const bf16x8*)&Plb[wave * 2304 + (mt * 16 + lane15) * 72 +
                                           c2 * 32 + quad * 8];
          la[mt] = __builtin_amdgcn_mfma_f32_16x16x32_bf16(pa, ones, la[mt], 0, 0, 0);
#pragma unroll
          for (int g2 = 0; g2 < 4; ++g2)
            o[mt][g2] = __builtin_amdgcn_mfma_f32_16x16x32_bf16(pa, vf[g2], o[mt][g2], 0, 0, 0);
        }
      }
      __syncthreads();
    }

    bf16* Oz = a.Opart + (size_t)sp * 4096 * 512;
#pragma unroll
    for (int mt = 0; mt < 2; ++mt) {
#pragma unroll
      for (int g2 = 0; g2 < 4; ++g2)
#pragma unroll
        for (int r = 0; r < 4; ++r) {
          const int row = qrow + mt * 16 + quad * 4 + r;
          Oz[(size_t)row * 512 + hd * 64 + g2 * 16 + lane15] = (bf16)o[mt][g2][r];
        }
      if (lane15 == 0) {
#pragma unroll
        for (int r = 0; r < 4; ++r)
          a.Lpart[sp * 32768 + (qrow + mt * 16 + quad * 4 + r) * 8 + hd] = la[mt][r];
      }
    }
  }
  gbar(a.bars + 2);

  // ---- S3: attention combine: ctx = sum O / sum l -------------------------
  for (int vb = bid; vb < 1024; vb += GRID) {
    const int g = vb * 256 + tid;
    const size_t base = (size_t)g * 8;
    const int row = g >> 6;
    const int hd  = (g & 63) >> 3;
    float acc[8] = {};
    float l = 0.0f;
#pragma unroll
    for (int s = 0; s < 4; ++s) {
      bf16x8 ov = *(const bf16x8*)&a.Opart[(size_t)s * 4096 * 512 + base];
#pragma unroll
      for (int j = 0; j < 8; ++j) acc[j] += (float)ov[j];
      l += a.Lpart[s * 32768 + row * 8 + hd];
    }
    const float rl = 1.0f / l;
    bf16x8 y;
#pragma unroll
    for (int j = 0; j < 8; ++j) y[j] = (bf16)(acc[j] * rl);
    *(bf16x8*)(a.ctx + base) = y;
  }
  gbar(a.bars + 3);

  // ---- S4: Wo projection, split-K x2 -> skP -------------------------------
  for (int vb = bid; vb < 512; vb += GRID) {
    const int m0 = (vb & 63) * 64, n0 = ((vb >> 6) & 3) * 128, z = vb >> 8;
    f32x4 acc[4][2] = {};
    gemm64(a.ctx, a.Wob, As, Bs, acc, 512, m0, n0, z * 256, z * 256 + 256);
    const int wn = wave << 5;
    float* Cz = a.skP + (size_t)z * 4096 * 512;
#pragma unroll
    for (int fm = 0; fm < 4; ++fm)
#pragma unroll
      for (int fn = 0; fn < 2; ++fn) {
        const int col = n0 + wn + fn * 16 + lane15;
#pragma unroll
        for (int r = 0; r < 4; ++r)
          Cz[(size_t)(m0 + fm * 16 + quad * 4 + r) * 512 + col] = acc[fm][fn][r];
      }
  }
  gbar(a.bars + 4);

  // ---- S5: h1 = LN(h + Wo-out + bo) ---------------------------------------
  for (int vb = bid; vb < 1024; vb += GRID)
    addln_body<0>(vb, a.hb, a.skP, a.bo, a.g1, a.be1, (void*)a.h1);
  gbar(a.bars + 5);

  // ---- S6: ff1 = relu(h1 @ W1^T + b1)  [4096x2048] ------------------------
  for (int vb = bid; vb < 1024; vb += GRID) {
    const int m0 = (vb & 63) * 64, n0 = (vb >> 6) * 128;
    f32x4 acc[4][2] = {};
    gemm64(a.h1, a.W1b, As, Bs, acc, 512, m0, n0, 0, 512);
    const int wn = wave << 5;
#pragma unroll
    for (int fm = 0; fm < 4; ++fm)
#pragma unroll
      for (int fn = 0; fn < 2; ++fn) {
        const int col = n0 + wn + fn * 16 + lane15;
        const float bv = a.b1[col];
#pragma unroll
        for (int r = 0; r < 4; ++r) {
          const int row = m0 + fm * 16 + quad * 4 + r;
          a.ff1[(size_t)row * 2048 + col] = (bf16)fmaxf(acc[fm][fn][r] + bv, 0.0f);
        }
      }
  }
  gbar(a.bars + 6);

  // ---- S7: ff2 split-K x2 -> skP  [K=2048] --------------------------------
  for (int vb = bid; vb < 512; vb += GRID) {
    const int m0 = (vb & 63) * 64, n0 = ((vb >> 6) & 3) * 128, z = vb >> 8;
    f32x4 acc[4][2] = {};
    gemm64(a.ff1, a.W2b, As, Bs, acc, 2048, m0, n0, z * 1024, z * 1024 + 1024);
    const int wn = wave << 5;
    float* Cz = a.skP + (size_t)z * 4096 * 512;
#pragma unroll
    for (int fm = 0; fm < 4; ++fm)
#pragma unroll
      for (int fn = 0; fn < 2; ++fn) {
        const int col = n0 + wn + fn * 16 + lane15;
#pragma unroll
        for (int r = 0; r < 4; ++r)
          Cz[(size_t)(m0 + fm * 16 + quad * 4 + r) * 512 + col] = acc[fm][fn][r];
      }
  }
  gbar(a.bars + 7);

  // ---- S8: out = LN(h1 + ff2 + b2)  (fp32) --------------------------------
  for (int vb = bid; vb < 1024; vb += GRID)
    addln_body<1>(vb, a.h1, a.skP, a.b2, a.g2, a.be2, (void*)a.out);
}

// ---------------------------------------------------------------------------
extern "C" void kernel_launch(void* const* d_in, const int* in_sizes, int n_in,
                              void* d_out, int out_size, void* d_ws, size_t ws_size,
                              hipStream_t stream)
{
  char* ws = (char*)d_ws;
  const size_t MB = 1024 * 1024;

  MegaArgs ma;
  ma.adj = (const int*)  d_in[1];
  ma.hf  = (const float*)d_in[0];
  ma.Wq  = (const float*)d_in[2];  ma.bq  = (const float*)d_in[3];
  ma.Wk  = (const float*)d_in[4];  ma.bk  = (const float*)d_in[5];
  ma.Wv  = (const float*)d_in[6];  ma.bv  = (const float*)d_in[7];
  ma.Wo  = (const float*)d_in[8];  ma.bo  = (const float*)d_in[9];
  ma.W1  = (const float*)d_in[10]; ma.b1  = (const float*)d_in[11];
  ma.W2  = (const float*)d_in[12]; ma.b2  = (const float*)d_in[13];
  ma.g1  = (const float*)d_in[14]; ma.be1 = (const float*)d_in[15];
  ma.g2  = (const float*)d_in[16]; ma.be2 = (const float*)d_in[17];

  // bf16 arena; Wq/Wk/Wv contiguous (concat [1536,512])
  ma.hb  = (bf16*)(ws + 0 * MB);
  ma.Wqb = (bf16*)(ws + 4 * MB);
  ma.Wkb = (bf16*)(ws + 4 * MB + 512 * 1024);
  ma.Wvb = (bf16*)(ws + 5 * MB);
  ma.Wob = (bf16*)(ws + 5 * MB + 512 * 1024);
  ma.W1b = (bf16*)(ws + 6 * MB);
  ma.W2b = (bf16*)(ws + 8 * MB);

  // intermediates (lifetime-packed, same plan as round 7)
  ma.q     = (bf16*)(ws + 12 * MB);
  ma.k     = (bf16*)(ws + 16 * MB);
  ma.vt    = (bf16*)(ws + 24 * MB);
  ma.mb    = (unsigned long long*)(ws + 28 * MB);
  ma.ctx   = (bf16*)(ws + 30 * MB);
  ma.Opart = (bf16*)(ws + 34 * MB);
  ma.Lpart = (float*)(ws + 50 * MB);
  ma.skP   = (float*)(ws + 34 * MB);   // over Opart (dead after S3)
  ma.h1    = (bf16*)(ws + 12 * MB);    // over q (dead after S2)
  ma.ff1   = (bf16*)(ws + 16 * MB);    // over k/vt/mbits/ctx (dead after S4)
  ma.out   = (float*)d_out;
  ma.bars  = (unsigned*)(ws + 51 * MB);

  hipMemsetAsync(ma.bars, 0, 64, stream);   // zero the 8 barrier counters
  k_mega<<<dim3(GRID), dim3(256), 0, stream>>>(ma);
}

// Round 10
// 1121.897 us; speedup vs baseline: 1.4626x; 1.4626x over previous
//
#include <hip/hip_runtime.h>
#include <stdint.h>
#include <stddef.h>

typedef __bf16 bf16;
typedef __bf16 bf16x8 __attribute__((ext_vector_type(8)));
typedef float  f32x4  __attribute__((ext_vector_type(4)));

typedef __attribute__((address_space(3))) void       lds_void;
typedef __attribute__((address_space(1))) const void gbl_cvoid;

#define ASYNC_CP16(g, l) \
  __builtin_amdgcn_global_load_lds((gbl_cvoid*)(g), (lds_void*)(l), 16, 0, 0)

#define GRID 1024

__device__ __forceinline__ int swz(int r) { return (r & 7) ^ ((r & 8) >> 1); }

// Software grid barrier. Round-9 lesson [measured]: spinning with ACQUIRE
// loads emits buffer_inv (L1+L2 invalidate) EVERY poll -> 1024 spinners
// thrash all 8 XCD L2s while late blocks still execute the stage (1.5 ms of
// near-idle). Fix: RELEASE arrive (one wbl2/block), RELAXED spin (agent-scope
// atomic loads read the coherence point, no invalidate), then ONE acquire
// load after the condition holds (single buffer_inv/block/barrier).
__device__ __forceinline__ void gbar(unsigned* cnt)
{
  __syncthreads();
  if (threadIdx.x == 0) {
    __hip_atomic_fetch_add(cnt, 1u, __ATOMIC_RELEASE, __HIP_MEMORY_SCOPE_AGENT);
    while (__hip_atomic_load(cnt, __ATOMIC_RELAXED, __HIP_MEMORY_SCOPE_AGENT) < GRID) {
      __builtin_amdgcn_s_sleep(32);
    }
    (void)__hip_atomic_load(cnt, __ATOMIC_ACQUIRE, __HIP_MEMORY_SCOPE_AGENT);
  }
  __syncthreads();
}

struct MegaArgs {
  const int*   adj;
  const float *hf, *Wq, *Wk, *Wv, *Wo, *W1, *W2;
  const float *bq, *bk, *bv, *bo, *b1, *b2, *g1, *be1, *g2, *be2;
  bf16 *hb, *Wqb, *Wkb, *Wvb, *Wob, *W1b, *W2b;
  bf16 *q, *k, *vt;
  unsigned long long* mb;
  bf16 *ctx, *Opart;
  float *Lpart, *skP;
  bf16 *h1, *ff1;
  float* out;
  unsigned* bars;
};

// ---------------------------------------------------------------------------
// MT=64 async-staged GEMM core: 64x128 tile, 4 waves (1x4), acc 4x2, BK=64.
// ---------------------------------------------------------------------------
__device__ __forceinline__ void gemm64(
    const bf16* A, const bf16* B, bf16* As, bf16* Bs,
    f32x4 (&acc)[4][2], int K, int m0, int n0, int kbeg, int kend)
{
  const int tid    = threadIdx.x;
  const int lane   = tid & 63;
  const int wave   = tid >> 6;
  const int lane15 = lane & 15;
  const int quad   = lane >> 4;
  const int wn     = wave << 5;

  int srA[2], soA[2], srB[4], soB[4];
#pragma unroll
  for (int i = 0; i < 2; ++i) {
    int c  = ((wave * 2 + i) << 6) + lane;
    srA[i] = c >> 3;
    soA[i] = ((c & 7) ^ swz(srA[i])) * 8;
  }
#pragma unroll
  for (int i = 0; i < 4; ++i) {
    int c  = ((wave * 4 + i) << 6) + lane;
    srB[i] = c >> 3;
    soB[i] = ((c & 7) ^ swz(srB[i])) * 8;
  }

  const bf16* Ab = A + (size_t)m0 * K;
  const bf16* Bb = B + (size_t)n0 * K;

  for (int k0 = kbeg; k0 < kend; k0 += 64) {
#pragma unroll
    for (int i = 0; i < 2; ++i)
      ASYNC_CP16(Ab + (size_t)srA[i] * K + k0 + soA[i], &As[(wave * 2 + i) * 512]);
#pragma unroll
    for (int i = 0; i < 4; ++i)
      ASYNC_CP16(Bb + (size_t)srB[i] * K + k0 + soB[i], &Bs[(wave * 4 + i) * 512]);
    __syncthreads();

#pragma unroll
    for (int kk = 0; kk < 2; ++kk) {
      bf16x8 af[4], bfr[2];
#pragma unroll
      for (int f = 0; f < 4; ++f) {
        const int ra = f * 16 + lane15;
        af[f] = *(const bf16x8*)&As[ra * 64 + (((kk * 4 + quad) ^ swz(ra)) * 8)];
      }
#pragma unroll
      for (int f = 0; f < 2; ++f) {
        const int rb = wn + f * 16 + lane15;
        bfr[f] = *(const bf16x8*)&Bs[rb * 64 + (((kk * 4 + quad) ^ swz(rb)) * 8)];
      }
#pragma unroll
      for (int fm = 0; fm < 4; ++fm)
#pragma unroll
        for (int fn = 0; fn < 2; ++fn)
          acc[fm][fn] = __builtin_amdgcn_mfma_f32_16x16x32_bf16(
              af[fm], bfr[fn], acc[fm][fn], 0, 0, 0);
    }
    __syncthreads();
  }
}

// ---------------------------------------------------------------------------
// split-K combine + bias + residual + LayerNorm (N=512), one row per wave x4.
// ---------------------------------------------------------------------------
template <int F32OUT>
__device__ __forceinline__ void addln_body(
    int vb, const bf16* x, const float* Cp, const float* bias,
    const float* gam, const float* bet, void* out)
{
  const int wave = threadIdx.x >> 6, lane = threadIdx.x & 63;
  const int row  = vb * 4 + wave;
  const size_t base = (size_t)row * 512 + lane * 8;
  const int col = lane * 8;
  bf16x8 xv = *(const bf16x8*)(x + base);
  const float* p0 = Cp + base;
  const float* p1 = Cp + (size_t)4096 * 512 + base;
  f32x4 a0 = *(const f32x4*)p0, a1 = *(const f32x4*)(p0 + 4);
  f32x4 b0 = *(const f32x4*)p1, b1 = *(const f32x4*)(p1 + 4);
  f32x4 c0 = *(const f32x4*)(bias + col), c1 = *(const f32x4*)(bias + col + 4);
  float v[8], s = 0.0f, s2 = 0.0f;
#pragma unroll
  for (int j = 0; j < 4; ++j) {
    v[j]     = (float)xv[j]     + a0[j] + b0[j] + c0[j];
    v[4 + j] = (float)xv[4 + j] + a1[j] + b1[j] + c1[j];
  }
#pragma unroll
  for (int j = 0; j < 8; ++j) { s += v[j]; s2 += v[j] * v[j]; }
#pragma unroll
  for (int d = 1; d < 64; d <<= 1) { s += __shfl_xor(s, d, 64); s2 += __shfl_xor(s2, d, 64); }
  const float mu  = s * (1.0f / 512.0f);
  const float var = s2 * (1.0f / 512.0f) - mu * mu;
  const float rs  = rsqrtf(var + 1e-5f);
  f32x4 g0 = *(const f32x4*)(gam + col), g1 = *(const f32x4*)(gam + col + 4);
  f32x4 e0 = *(const f32x4*)(bet + col), e1 = *(const f32x4*)(bet + col + 4);
  if (F32OUT) {
    float* o = (float*)out + base;
#pragma unroll
    for (int j = 0; j < 4; ++j) {
      o[j]     = ((v[j] - mu) * rs) * g0[j] + e0[j];
      o[4 + j] = ((v[4 + j] - mu) * rs) * g1[j] + e1[j];
    }
  } else {
    bf16x8 ov;
#pragma unroll
    for (int j = 0; j < 4; ++j) {
      ov[j]     = (bf16)(((v[j] - mu) * rs) * g0[j] + e0[j]);
      ov[4 + j] = (bf16)(((v[4 + j] - mu) * rs) * g1[j] + e1[j]);
    }
    *(bf16x8*)((bf16*)out + base) = ov;
  }
}

// ---------------------------------------------------------------------------
// The mega-kernel: 9 stages, 8 software grid barriers, one normal launch.
// ---------------------------------------------------------------------------
__global__ __launch_bounds__(256, 4) void k_mega(MegaArgs a)
{
  __shared__ __align__(16) char smem[34816];
  bf16* As  = (bf16*)smem;             // 8 KB   (GEMM A / attn Ks)
  bf16* Bs  = (bf16*)(smem + 8192);    // 16 KB  (GEMM B / attn Vs)
  bf16* Plb = (bf16*)(smem + 16384);   // 18 KB  (attn P, 4 waves x 32x72)

  const int bid    = blockIdx.x;
  const int tid    = threadIdx.x;
  const int lane   = tid & 63;
  const int wave   = tid >> 6;
  const int lane15 = lane & 15;
  const int quad   = lane >> 4;

  // ---- S0: pack adjacency(+I) into bitmask + fp32->bf16 cast --------------
  for (int vb = bid; vb < 68096; vb += GRID) {
    if (vb < 65536) {
      const int gw = vb * 4 + wave;
      const int av = a.adj[(size_t)gw * 64 + lane];
      unsigned long long m = __ballot(av != 0);
      const int row = gw >> 6, wc = gw & 63;
      if ((row >> 6) == wc) m |= 1ull << (row & 63);
      if (lane == 0) a.mb[gw] = m;
    } else {
      const int t = vb - 65536;
      const float* src; bf16* dst; int i;
      if (t < 1024)      { src = a.hf; dst = a.hb;  i = t * 256 + tid; }
      else if (t < 1152) { src = a.Wq; dst = a.Wqb; i = (t - 1024) * 256 + tid; }
      else if (t < 1280) { src = a.Wk; dst = a.Wkb; i = (t - 1152) * 256 + tid; }
      else if (t < 1408) { src = a.Wv; dst = a.Wvb; i = (t - 1280) * 256 + tid; }
      else if (t < 1536) { src = a.Wo; dst = a.Wob; i = (t - 1408) * 256 + tid; }
      else if (t < 2048) { src = a.W1; dst = a.W1b; i = (t - 1536) * 256 + tid; }
      else               { src = a.W2; dst = a.W2b; i = (t - 2048) * 256 + tid; }
      const float4* s = (const float4*)src + (size_t)i * 2;
      const float4 x0 = s[0], x1 = s[1];
      bf16x8 y;
      y[0] = (bf16)x0.x; y[1] = (bf16)x0.y; y[2] = (bf16)x0.z; y[3] = (bf16)x0.w;
      y[4] = (bf16)x1.x; y[5] = (bf16)x1.y; y[6] = (bf16)x1.z; y[7] = (bf16)x1.w;
      *(bf16x8*)(dst + (size_t)i * 8) = y;
    }
  }
  gbar(a.bars + 0);

  // ---- S1: QKV projection (concat W [1536,512]); V blocks write vt --------
  for (int vb = bid; vb < 768; vb += GRID) {
    const int m0 = (vb & 63) * 64, n0 = (vb >> 6) * 128;
    f32x4 acc[4][2] = {};
    gemm64(a.hb, a.Wqb, As, Bs, acc, 512, m0, n0, 0, 512);
    const int wn = wave << 5;
    const int proj = n0 >> 9;
    const int ncol0 = n0 & 511;
    const float* bias = (proj == 0) ? a.bq : (proj == 1) ? a.bk : a.bv;
    if (proj < 2) {
      bf16* C = proj ? a.k : a.q;
#pragma unroll
      for (int fm = 0; fm < 4; ++fm)
#pragma unroll
        for (int fn = 0; fn < 2; ++fn) {
          const int col = ncol0 + wn + fn * 16 + lane15;
          const float bvv = bias[col];
#pragma unroll
          for (int r = 0; r < 4; ++r) {
            const int row = m0 + fm * 16 + quad * 4 + r;
            C[(size_t)row * 512 + col] = (bf16)(acc[fm][fn][r] + bvv);
          }
        }
    } else {
      __syncthreads();   // K-loop LDS dead
      bf16* SM = As;     // transpose scratch: 128*72*2 = 18432B < 34816B
#pragma unroll
      for (int fm = 0; fm < 4; ++fm)
#pragma unroll
        for (int fn = 0; fn < 2; ++fn) {
          const int colL = wn + fn * 16 + lane15;
          const float bvv = bias[ncol0 + colL];
#pragma unroll
          for (int r = 0; r < 4; ++r) {
            const int rowL = fm * 16 + quad * 4 + r;
            SM[colL * 72 + rowL] = (bf16)(acc[fm][fn][r] + bvv);
          }
        }
      __syncthreads();
#pragma unroll
      for (int i = 0; i < 4; ++i) {
        const int c = i * 256 + tid;
        const int colL = c >> 3, rw = (c & 7) * 8;
        *(bf16x8*)&a.vt[(size_t)(ncol0 + colL) * 4096 + m0 + rw] =
            *(const bf16x8*)&SM[colL * 72 + rw];
      }
      __syncthreads();
    }
  }
  gbar(a.bars + 1);

  // ---- S2: flash attention, split-K x4, 32 q-rows/wave --------------------
  {
    const int vb = bid;
    bf16* Ks = As;
    bf16* Vs = Bs;
    const int sp = vb & 3;
    const int hd = (vb >> 2) & 7;
    const int qt = vb >> 5;
    const int qrow = qt * 128 + wave * 32;

    bf16x8 qf[2][2];
#pragma unroll
    for (int mt = 0; mt < 2; ++mt)
#pragma unroll
      for (int c = 0; c < 2; ++c)
        qf[mt][c] = *(const bf16x8*)&a.q[(size_t)(qrow + mt * 16 + lane15) * 512 +
                                         hd * 64 + c * 32 + quad * 8];

    int srK[2], soK[2];
#pragma unroll
    for (int i = 0; i < 2; ++i) {
      int c  = ((wave * 2 + i) << 6) + lane;
      srK[i] = c >> 3;
      soK[i] = ((c & 7) ^ swz(srK[i])) * 8;
    }
    const bf16* KmB[2] = {
        a.k + (size_t)srK[0] * 512 + hd * 64 + soK[0],
        a.k + (size_t)srK[1] * 512 + hd * 64 + soK[1]};
    const bf16* VtB[2] = {
        a.vt + (size_t)(hd * 64 + srK[0]) * 4096 + soK[0],
        a.vt + (size_t)(hd * 64 + srK[1]) * 4096 + soK[1]};

    bf16x8 ones;
#pragma unroll
    for (int j = 0; j < 8; ++j) ones[j] = (bf16)1.0f;

    f32x4 o[2][4] = {};
    f32x4 la[2]   = {};

    for (int kt = sp * 16; kt < sp * 16 + 16; ++kt) {
      const int kb = kt * 64;
#pragma unroll
      for (int i = 0; i < 2; ++i) {
        ASYNC_CP16(KmB[i] + (size_t)kb * 512, &Ks[(wave * 2 + i) * 512]);
        ASYNC_CP16(VtB[i] + kb,               &Vs[(wave * 2 + i) * 512]);
      }
      __syncthreads();

      unsigned long long mw[2][4];
#pragma unroll
      for (int mt = 0; mt < 2; ++mt)
#pragma unroll
        for (int r = 0; r < 4; ++r)
          mw[mt][r] = a.mb[(size_t)(qrow + mt * 16 + quad * 4 + r) * 64 + kt] >> lane15;

#pragma unroll
      for (int g = 0; g < 4; ++g) {
        const int row = g * 16 + lane15;
        bf16x8 k0f = *(const bf16x8*)&Ks[row * 64 + ((quad       ^ swz(row)) * 8)];
        bf16x8 k1f = *(const bf16x8*)&Ks[row * 64 + (((4 + quad) ^ swz(row)) * 8)];
#pragma unroll
        for (int mt = 0; mt < 2; ++mt) {
          f32x4 s = {};
          s = __builtin_amdgcn_mfma_f32_16x16x32_bf16(qf[mt][0], k0f, s, 0, 0, 0);
          s = __builtin_amdgcn_mfma_f32_16x16x32_bf16(qf[mt][1], k1f, s, 0, 0, 0);
#pragma unroll
          for (int r = 0; r < 4; ++r) {
            const bool ok = ((mw[mt][r] >> (g * 16)) & 1ull) != 0;
            const float p = ok ? __expf(s[r] * 0.125f) : 0.0f;
            Plb[wave * 2304 + (mt * 16 + quad * 4 + r) * 72 + g * 16 + lane15] = (bf16)p;
          }
        }
      }

#pragma unroll
      for (int c2 = 0; c2 < 2; ++c2) {
        bf16x8 vf[4];
#pragma unroll
        for (int g2 = 0; g2 < 4; ++g2) {
          const int row = g2 * 16 + lane15;
          vf[g2] = *(const bf16x8*)&Vs[row * 64 + (((c2 * 4 + quad) ^ swz(row)) * 8)];
        }
#pragma unroll
        for (int mt = 0; mt < 2; ++mt) {
          bf16x8 pa = *(const bf16x8*)&Plb[wave * 2304 + (mt * 16 + lane15) * 72 +
                                           c2 * 32 + quad * 8];
          la[mt] = __builtin_amdgcn_mfma_f32_16x16x32_bf16(pa, ones, la[mt], 0, 0, 0);
#pragma unroll
          for (int g2 = 0; g2 < 4; ++g2)
            o[mt][g2] = __builtin_amdgcn_mfma_f32_16x16x32_bf16(pa, vf[g2], o[mt][g2], 0, 0, 0);
        }
      }
      __syncthreads();
    }

    bf16* Oz = a.Opart + (size_t)sp * 4096 * 512;
#pragma unroll
    for (int mt = 0; mt < 2; ++mt) {
#pragma unroll
      for (int g2 = 0; g2 < 4; ++g2)
#pragma unroll
        for (int r = 0; r < 4; ++r) {
          const int row = qrow + mt * 16 + quad * 4 + r;
          Oz[(size_t)row * 512 + hd * 64 + g2 * 16 + lane15] = (bf16)o[mt][g2][r];
        }
      if (lane15 == 0) {
#pragma unroll
        for (int r = 0; r < 4; ++r)
          a.Lpart[sp * 32768 + (qrow + mt * 16 + quad * 4 + r) * 8 + hd] = la[mt][r];
      }
    }
  }
  gbar(a.bars + 2);

  // ---- S3: attention combine: ctx = sum O / sum l -------------------------
  for (int vb = bid; vb < 1024; vb += GRID) {
    const int g = vb * 256 + tid;
    const size_t base = (size_t)g * 8;
    const int row = g >> 6;
    const int hd  = (g & 63) >> 3;
    float acc[8] = {};
    float l = 0.0f;
#pragma unroll
    for (int s = 0; s < 4; ++s) {
      bf16x8 ov = *(const bf16x8*)&a.Opart[(size_t)s * 4096 * 512 + base];
#pragma unroll
      for (int j = 0; j < 8; ++j) acc[j] += (float)ov[j];
      l += a.Lpart[s * 32768 + row * 8 + hd];
    }
    const float rl = 1.0f / l;
    bf16x8 y;
#pragma unroll
    for (int j = 0; j < 8; ++j) y[j] = (bf16)(acc[j] * rl);
    *(bf16x8*)(a.ctx + base) = y;
  }
  gbar(a.bars + 3);

  // ---- S4: Wo projection, split-K x2 -> skP -------------------------------
  for (int vb = bid; vb < 512; vb += GRID) {
    const int m0 = (vb & 63) * 64, n0 = ((vb >> 6) & 3) * 128, z = vb >> 8;
    f32x4 acc[4][2] = {};
    gemm64(a.ctx, a.Wob, As, Bs, acc, 512, m0, n0, z * 256, z * 256 + 256);
    const int wn = wave << 5;
    float* Cz = a.skP + (size_t)z * 4096 * 512;
#pragma unroll
    for (int fm = 0; fm < 4; ++fm)
#pragma unroll
      for (int fn = 0; fn < 2; ++fn) {
        const int col = n0 + wn + fn * 16 + lane15;
#pragma unroll
        for (int r = 0; r < 4; ++r)
          Cz[(size_t)(m0 + fm * 16 + quad * 4 + r) * 512 + col] = acc[fm][fn][r];
      }
  }
  gbar(a.bars + 4);

  // ---- S5: h1 = LN(h + Wo-out + bo) ---------------------------------------
  for (int vb = bid; vb < 1024; vb += GRID)
    addln_body<0>(vb, a.hb, a.skP, a.bo, a.g1, a.be1, (void*)a.h1);
  gbar(a.bars + 5);

  // ---- S6: ff1 = relu(h1 @ W1^T + b1)  [4096x2048] ------------------------
  for (int vb = bid; vb < 1024; vb += GRID) {
    const int m0 = (vb & 63) * 64, n0 = (vb >> 6) * 128;
    f32x4 acc[4][2] = {};
    gemm64(a.h1, a.W1b, As, Bs, acc, 512, m0, n0, 0, 512);
    const int wn = wave << 5;
#pragma unroll
    for (int fm = 0; fm < 4; ++fm)
#pragma unroll
      for (int fn = 0; fn < 2; ++fn) {
        const int col = n0 + wn + fn * 16 + lane15;
        const float bv = a.b1[col];
#pragma unroll
        for (int r = 0; r < 4; ++r) {
          const int row = m0 + fm * 16 + quad * 4 + r;
          a.ff1[(size_t)row * 2048 + col] = (bf16)fmaxf(acc[fm][fn][r] + bv, 0.0f);
        }
      }
  }
  gbar(a.bars + 6);

  // ---- S7: ff2 split-K x2 -> skP  [K=2048] --------------------------------
  for (int vb = bid; vb < 512; vb += GRID) {
    const int m0 = (vb & 63) * 64, n0 = ((vb >> 6) & 3) * 128, z = vb >> 8;
    f32x4 acc[4][2] = {};
    gemm64(a.ff1, a.W2b, As, Bs, acc, 2048, m0, n0, z * 1024, z * 1024 + 1024);
    const int wn = wave << 5;
    float* Cz = a.skP + (size_t)z * 4096 * 512;
#pragma unroll
    for (int fm = 0; fm < 4; ++fm)
#pragma unroll
      for (int fn = 0; fn < 2; ++fn) {
        const int col = n0 + wn + fn * 16 + lane15;
#pragma unroll
        for (int r = 0; r < 4; ++r)
          Cz[(size_t)(m0 + fm * 16 + quad * 4 + r) * 512 + col] = acc[fm][fn][r];
      }
  }
  gbar(a.bars + 7);

  // ---- S8: out = LN(h1 + ff2 + b2)  (fp32) --------------------------------
  for (int vb = bid; vb < 1024; vb += GRID)
    addln_body<1>(vb, a.h1, a.skP, a.b2, a.g2, a.be2, (void*)a.out);
}

// ---------------------------------------------------------------------------
extern "C" void kernel_launch(void* const* d_in, const int* in_sizes, int n_in,
                              void* d_out, int out_size, void* d_ws, size_t ws_size,
                              hipStream_t stream)
{
  char* ws = (char*)d_ws;
  const size_t MB = 1024 * 1024;

  MegaArgs ma;
  ma.adj = (const int*)  d_in[1];
  ma.hf  = (const float*)d_in[0];
  ma.Wq  = (const float*)d_in[2];  ma.bq  = (const float*)d_in[3];
  ma.Wk  = (const float*)d_in[4];  ma.bk  = (const float*)d_in[5];
  ma.Wv  = (const float*)d_in[6];  ma.bv  = (const float*)d_in[7];
  ma.Wo  = (const float*)d_in[8];  ma.bo  = (const float*)d_in[9];
  ma.W1  = (const float*)d_in[10]; ma.b1  = (const float*)d_in[11];
  ma.W2  = (const float*)d_in[12]; ma.b2  = (const float*)d_in[13];
  ma.g1  = (const float*)d_in[14]; ma.be1 = (const float*)d_in[15];
  ma.g2  = (const float*)d_in[16]; ma.be2 = (const float*)d_in[17];

  // bf16 arena; Wq/Wk/Wv contiguous (concat [1536,512])
  ma.hb  = (bf16*)(ws + 0 * MB);
  ma.Wqb = (bf16*)(ws + 4 * MB);
  ma.Wkb = (bf16*)(ws + 4 * MB + 512 * 1024);
  ma.Wvb = (bf16*)(ws + 5 * MB);
  ma.Wob = (bf16*)(ws + 5 * MB + 512 * 1024);
  ma.W1b = (bf16*)(ws + 6 * MB);
  ma.W2b = (bf16*)(ws + 8 * MB);

  // intermediates (lifetime-packed, same plan as round 7)
  ma.q     = (bf16*)(ws + 12 * MB);
  ma.k     = (bf16*)(ws + 16 * MB);
  ma.vt    = (bf16*)(ws + 24 * MB);
  ma.mb    = (unsigned long long*)(ws + 28 * MB);
  ma.ctx   = (bf16*)(ws + 30 * MB);
  ma.Opart = (bf16*)(ws + 34 * MB);
  ma.Lpart = (float*)(ws + 50 * MB);
  ma.skP   = (float*)(ws + 34 * MB);   // over Opart (dead after S3)
  ma.h1    = (bf16*)(ws + 12 * MB);    // over q (dead after S2)
  ma.ff1   = (bf16*)(ws + 16 * MB);    // over k/vt/mbits/ctx (dead after S4)
  ma.out   = (float*)d_out;
  ma.bars  = (unsigned*)(ws + 51 * MB);

  hipMemsetAsync(ma.bars, 0, 64, stream);   // zero the 8 barrier counters
  k_mega<<<dim3(GRID), dim3(256), 0, stream>>>(ma);
}